// Round 17
// baseline (685.145 us; speedup 1.0000x reference)
//
#include <hip/hip_runtime.h>
#include <hip/hip_bf16.h>

// BS=2, C=32, S=64.
// ws: [0, 96 MiB)    xblk bf16 [b][ciq][64^3][32]  (blocked channels-last)
//     [48, 96 MiB)   (alias) qF,kF,vF f16 [c][h][w][d] — live only between
//                    trans_b and repack_b of the same batch (xblk[b=1] region)
//     [96, 112 MiB)  y0   bf16 [c][s][4096]
//     [112,128 MiB)  qT   f16  [c][d][w][h]
//     [128,144 MiB)  kT   f16  (aliased as y1 after attn<0>)
//     [144,160 MiB)  vT   f16  (aliased as y2 after attn<0>)
//     [160 MiB,+166K) wt2 bf16 [tap][ciq][oct][co][8]
// out: (2,32,64,64,64) fp32.

#define CH 32

typedef __attribute__((ext_vector_type(8))) _Float16 f16x8;
typedef __attribute__((ext_vector_type(4))) _Float16 f16x4;
typedef __attribute__((ext_vector_type(8))) short bf16x8;
typedef __attribute__((ext_vector_type(4))) float f32x4;

static __device__ __forceinline__ unsigned short f2bf(float f) {
  union { float f; unsigned u; } x; x.f = f;
  unsigned r = x.u + 0x7fff + ((x.u >> 16) & 1);   // RNE
  return (unsigned short)(r >> 16);
}

// ---------------------------------------------------------------------------
// trans_dwh: q/k/v f32 [c][h][w][d] -> f16 [c][d][w][h] (qT/kT/vT for BR0)
// AND f16 same-layout copies [c][h][w][d] (qF/kF/vF for BR1/2).
// ---------------------------------------------------------------------------
__global__ __launch_bounds__(256) void trans_dwh(const float* __restrict__ q,
                                                 const float* __restrict__ k,
                                                 const float* __restrict__ v,
                                                 _Float16* __restrict__ qT,
                                                 _Float16* __restrict__ kT,
                                                 _Float16* __restrict__ vT,
                                                 _Float16* __restrict__ qF,
                                                 _Float16* __restrict__ kF,
                                                 _Float16* __restrict__ vF,
                                                 int b) {
  __shared__ __align__(16) _Float16 Ls[64 * 72];
  const int blk = blockIdx.x;          // 2048 = c*64 + w
  const int c = blk >> 6;
  const int w = blk & 63;
  const int tid = threadIdx.x;
  const size_t bc = (size_t)(b * CH + c);
  const float* srcs[3] = {q, k, v};
  _Float16* dsts[3] = {qT, kT, vT};
  _Float16* dstsF[3] = {qF, kF, vF};
  const int h = tid >> 2, dq = tid & 3;

  for (int tz = 0; tz < 3; ++tz) {
    const float* sp = srcs[tz] + bc * 262144 + (size_t)h * 4096 + (size_t)w * 64;
    float4 ld[4];
    #pragma unroll
    for (int pp = 0; pp < 4; ++pp) {
      const int d0 = dq * 16 + pp * 4;
      ld[pp] = *(const float4*)(sp + d0);
      Ls[(d0 + 0) * 72 + h] = (_Float16)ld[pp].x;
      Ls[(d0 + 1) * 72 + h] = (_Float16)ld[pp].y;
      Ls[(d0 + 2) * 72 + h] = (_Float16)ld[pp].z;
      Ls[(d0 + 3) * 72 + h] = (_Float16)ld[pp].w;
    }
    // same-layout f16 copy: contiguous 16B x2 per thread
    {
      _Float16* fp = dstsF[tz] + (size_t)c * 262144 + (size_t)h * 4096 +
                     (size_t)w * 64 + dq * 16;
      f16x8 lo8 = {(_Float16)ld[0].x, (_Float16)ld[0].y, (_Float16)ld[0].z, (_Float16)ld[0].w,
                   (_Float16)ld[1].x, (_Float16)ld[1].y, (_Float16)ld[1].z, (_Float16)ld[1].w};
      f16x8 hi8 = {(_Float16)ld[2].x, (_Float16)ld[2].y, (_Float16)ld[2].z, (_Float16)ld[2].w,
                   (_Float16)ld[3].x, (_Float16)ld[3].y, (_Float16)ld[3].z, (_Float16)ld[3].w};
      *(f16x8*)(fp) = lo8;
      *(f16x8*)(fp + 8) = hi8;
    }
    __syncthreads();
    _Float16* dp = dsts[tz] + (size_t)c * 262144 + (size_t)w * 64;
    #pragma unroll
    for (int p = 0; p < 2; ++p) {
      const int idx = p * 256 + tid;
      const int d = idx >> 3, o = (idx & 7) * 8;
      *(f16x8*)(dp + (size_t)d * 4096 + o) = *(const f16x8*)&Ls[d * 72 + o];
    }
    __syncthreads();
  }
}

// ---------------------------------------------------------------------------
// Axial attention via f16 MFMA (round-16 verbatim).
// ---------------------------------------------------------------------------
template <int BR>
__global__ __launch_bounds__(256) void attn_mfma(const _Float16* __restrict__ qT,
                                                 const _Float16* __restrict__ kT,
                                                 const _Float16* __restrict__ vT,
                                                 const _Float16* __restrict__ qF,
                                                 const _Float16* __restrict__ kF,
                                                 const _Float16* __restrict__ vF,
                                                 unsigned short* __restrict__ ybr) {
  __shared__ __align__(16) _Float16 Qh[64][72];
  __shared__ __align__(16) _Float16 Kh[64][72];
  __shared__ __align__(16) _Float16 Vh[64][72];

  const int blk0 = blockIdx.x;
  const int blk = ((blk0 & 7) << 8) | (blk0 >> 3);   // XCD chunk (2048 = 8*256)
  const int s = blk & 63;
  const int c = blk >> 6;
  const int tid = threadIdx.x;

  if (BR == 0) {
    const _Float16* qp = qT + ((size_t)c * 64 + s) * 4096;
    const _Float16* kp = kT + ((size_t)c * 64 + s) * 4096;
    const _Float16* vp = vT + ((size_t)c * 64 + s) * 4096;
    #pragma unroll
    for (int ii = 0; ii < 2; ++ii) {
      const int idx = ii * 256 + tid;
      const int row = idx >> 3, ch = (idx & 7) * 8;
      *(f16x8*)&Qh[row][ch] = *(const f16x8*)(qp + row * 64 + ch);
      *(f16x8*)&Kh[row][ch] = *(const f16x8*)(kp + row * 64 + ch);
      *(f16x8*)&Vh[row][ch] = *(const f16x8*)(vp + row * 64 + ch);   // Vt[t][j]
    }
  } else {
    const size_t base = (size_t)c * 262144;
    #pragma unroll
    for (int ii = 0; ii < 2; ++ii) {
      const int idx = ii * 256 + tid;
      const int row = idx >> 3, ch = (idx & 7) * 8;
      size_t off;
      if (BR == 1) off = (size_t)row * 4096 + (size_t)s * 64 + ch;
      else         off = (size_t)s * 4096 + (size_t)row * 64 + ch;
      *(f16x8*)&Qh[row][ch] = *(const f16x8*)(qF + base + off);
      *(f16x8*)&Kh[row][ch] = *(const f16x8*)(kF + base + off);
      *(f16x8*)&Vh[row][ch] = *(const f16x8*)(vF + base + off);     // Vh[j][t]
    }
  }
  __syncthreads();

  const int w = tid >> 6;
  const int lane = tid & 63;
  const int r = lane & 15;
  const int oct = lane >> 4;

  f32x4 sc[4];
  #pragma unroll
  for (int jt = 0; jt < 4; ++jt) sc[jt] = (f32x4){0.f, 0.f, 0.f, 0.f};
  f16x8 aq0 = *(const f16x8*)&Qh[w * 16 + r][oct * 8];
  f16x8 aq1 = *(const f16x8*)&Qh[w * 16 + r][32 + oct * 8];
  #pragma unroll
  for (int jt = 0; jt < 4; ++jt) {
    f16x8 bk0 = *(const f16x8*)&Kh[jt * 16 + r][oct * 8];
    f16x8 bk1 = *(const f16x8*)&Kh[jt * 16 + r][32 + oct * 8];
    sc[jt] = __builtin_amdgcn_mfma_f32_16x16x32_f16(aq0, bk0, sc[jt], 0, 0, 0);
    sc[jt] = __builtin_amdgcn_mfma_f32_16x16x32_f16(aq1, bk1, sc[jt], 0, 0, 0);
  }

  float P[4][4];
  #pragma unroll
  for (int reg = 0; reg < 4; ++reg) {
    float mx = fmaxf(fmaxf(sc[0][reg], sc[1][reg]), fmaxf(sc[2][reg], sc[3][reg]));
    mx = fmaxf(mx, __shfl_xor(mx, 1));
    mx = fmaxf(mx, __shfl_xor(mx, 2));
    mx = fmaxf(mx, __shfl_xor(mx, 4));
    mx = fmaxf(mx, __shfl_xor(mx, 8));
    float e[4], sum = 0.f;
    #pragma unroll
    for (int jt = 0; jt < 4; ++jt) { e[jt] = __expf(sc[jt][reg] - mx); sum += e[jt]; }
    sum += __shfl_xor(sum, 1);
    sum += __shfl_xor(sum, 2);
    sum += __shfl_xor(sum, 4);
    sum += __shfl_xor(sum, 8);
    const float inv = 1.f / sum;
    #pragma unroll
    for (int jt = 0; jt < 4; ++jt) P[reg][jt] = e[jt] * inv;
  }

  #pragma unroll
  for (int reg = 0; reg < 4; ++reg)
    #pragma unroll
    for (int jt = 0; jt < 4; ++jt)
      Qh[w * 16 + oct * 4 + reg][jt * 16 + r] = (_Float16)P[reg][jt];

  f16x8 ap0 = *(const f16x8*)&Qh[w * 16 + r][oct * 8];
  f16x8 ap1 = *(const f16x8*)&Qh[w * 16 + r][32 + oct * 8];
  f32x4 ot[4];
  #pragma unroll
  for (int tt = 0; tt < 4; ++tt) {
    ot[tt] = (f32x4){0.f, 0.f, 0.f, 0.f};
    f16x8 bv0, bv1;
    if (BR == 0) {
      bv0 = *(const f16x8*)&Vh[tt * 16 + r][oct * 8];
      bv1 = *(const f16x8*)&Vh[tt * 16 + r][32 + oct * 8];
    } else {
      #pragma unroll
      for (int e = 0; e < 8; ++e) {
        bv0[e] = Vh[oct * 8 + e][tt * 16 + r];
        bv1[e] = Vh[32 + oct * 8 + e][tt * 16 + r];
      }
    }
    ot[tt] = __builtin_amdgcn_mfma_f32_16x16x32_f16(ap0, bv0, ot[tt], 0, 0, 0);
    ot[tt] = __builtin_amdgcn_mfma_f32_16x16x32_f16(ap1, bv1, ot[tt], 0, 0, 0);
  }

  __syncthreads();
  unsigned short* Ot = (unsigned short*)&Kh[0][0];   // stride 72
  #pragma unroll
  for (int tt = 0; tt < 4; ++tt)
    #pragma unroll
    for (int reg = 0; reg < 4; ++reg)
      Ot[(size_t)(w * 16 + oct * 4 + reg) * 72 + tt * 16 + r] = f2bf(ot[tt][reg]);
  __syncthreads();

  {
    const int i = tid >> 2, seg = tid & 3;
    const unsigned short* src = Ot + (size_t)i * 72 + seg * 16;
    bf16x8 a0 = *(const bf16x8*)(src);
    bf16x8 a1 = *(const bf16x8*)(src + 8);
    unsigned short* dst = ybr + ((size_t)(c * 64 + s)) * 4096 + tid * 16;
    *(bf16x8*)(dst) = a0;
    *(bf16x8*)(dst + 8) = a1;
  }
}

// ---------------------------------------------------------------------------
// repack_all: all 3 branches in one dispatch (grid 1536 = br*512 + inner).
// ---------------------------------------------------------------------------
__global__ __launch_bounds__(256) void repack_all(const unsigned short* __restrict__ y0p,
                                                  const unsigned short* __restrict__ y1p,
                                                  const unsigned short* __restrict__ y2p,
                                                  unsigned short* __restrict__ xblk,
                                                  int b) {
  __shared__ unsigned short Ls[32 * 530];
  const int blk = blockIdx.x;        // 1536
  const int br = blk >> 9;           // 0..2
  const int inner = blk & 511;
  const int oc = inner & 7;
  const int z = inner >> 3;
  const int tid = threadIdx.x;
  const int c = tid & 31;
  const int w8 = tid >> 5;           // 0..7

  const unsigned short* ybr = (br == 0) ? y0p : (br == 1) ? y1p : y2p;

  size_t src;
  if (br == 2) src = ((size_t)(c * 64 + z)) * 4096 + (size_t)(oc * 8 + w8) * 64;
  else         src = ((size_t)(c * 64 + oc * 8 + w8)) * 4096 + (size_t)z * 64;

  #pragma unroll
  for (int kk = 0; kk < 8; ++kk) {
    bf16x8 vv = *(const bf16x8*)(ybr + src + kk * 8);
    #pragma unroll
    for (int e = 0; e < 8; ++e) {
      const int l = kk * 8 + e;
      const int li = (br == 0) ? (l * 8 + w8) : (w8 * 64 + l);
      Ls[c * 530 + li] = (unsigned short)vv[e];
    }
  }
  __syncthreads();

  unsigned short* xq = xblk + ((size_t)(b * 3 + br)) * 262144 * 32;
  #pragma unroll
  for (int p = 0; p < 2; ++p) {
    const int o = p * 256 + tid;
    bf16x8 o0, o1, o2, o3;
    #pragma unroll
    for (int e = 0; e < 8; ++e) {
      o0[e] = (short)Ls[(e)      * 530 + o];
      o1[e] = (short)Ls[(8 + e)  * 530 + o];
      o2[e] = (short)Ls[(16 + e) * 530 + o];
      o3[e] = (short)Ls[(24 + e) * 530 + o];
    }
    int sp;
    if (br == 0) sp = z * 4096 + (o >> 3) * 64 + oc * 8 + (o & 7);
    else         sp = z * 4096 + oc * 512 + o;
    unsigned short* dst = xq + (size_t)sp * 32;
    *(bf16x8*)(dst)      = o0;
    *(bf16x8*)(dst + 8)  = o1;
    *(bf16x8*)(dst + 16) = o2;
    *(bf16x8*)(dst + 24) = o3;
  }
}

// w[co][ci][dz][dy][dx] f32 -> wt2 bf16, idx = (((tap*3+ciq)*4+oct)*32 + co)*8 + e
__global__ __launch_bounds__(256) void wprep(const float* __restrict__ w,
                                             unsigned short* __restrict__ wt2) {
  int idx = blockIdx.x * 256 + threadIdx.x;
  if (idx >= 27 * 32 * 96) return;
  int tap = idx / 3072;
  int rem = idx - tap * 3072;
  int co = rem / 96, ci = rem - co * 96;
  int ciq = ci >> 5, oct = (ci >> 3) & 3, e = ci & 7;
  wt2[(((tap * 3 + ciq) * 4 + oct) * 32 + co) * 8 + e] =
      f2bf(w[((size_t)co * 96 + ci) * 27 + tap]);
}

// ---------------------------------------------------------------------------
// Z-PAIR conv, R8 structure + T14 async-STAGE split: LOADR(t+1) issues the
// 11x16B global loads into registers BEFORE COMPUTE(t) (latency hides under
// the 288-MFMA cluster); WRITEB lands them in LDS after the barrier. Single
// 47.6KB buffer (barrier after COMPUTE makes overwrite safe); 2 barriers per
// stage, same as R8. (256,2), grid 512.
// ---------------------------------------------------------------------------
__global__ __launch_bounds__(256, 2) void conv_mfma(const unsigned short* __restrict__ xblk,
                                                    const unsigned short* __restrict__ wt2,
                                                    const float* __restrict__ cb,
                                                    const float* __restrict__ gamma,
                                                    const float* __restrict__ beta,
                                                    const float* __restrict__ mean,
                                                    const float* __restrict__ var,
                                                    float* __restrict__ out) {
  __shared__ __align__(16) unsigned short XT[23760];   // 10*66*36 shorts

  const int blk0 = blockIdx.x;                       // 512
  const int blk = ((blk0 & 7) << 6) | (blk0 >> 3);   // XCD chunk (512 = 8*64)
  const int yt = blk & 7;
  const int zp = (blk >> 3) & 31;
  const int b = blk >> 8;                            // 0..1
  const int tid = threadIdx.x;
  const int w = tid >> 6;
  const int lane = tid & 63;
  const int r = lane & 15;
  const int oct = lane >> 4;
  const int y0 = yt * 8;
  const int z0 = zp * 2;

  f32x4 acc0[2][4][2], acc1[2][4][2];
  #pragma unroll
  for (int ry = 0; ry < 2; ++ry)
    #pragma unroll
    for (int xc = 0; xc < 4; ++xc)
      #pragma unroll
      for (int ct = 0; ct < 2; ++ct) {
        acc0[ry][xc][ct] = (f32x4){0.f, 0.f, 0.f, 0.f};
        acc1[ry][xc][ct] = (f32x4){0.f, 0.f, 0.f, 0.f};
      }

  bf16x8 rv[11];

  auto LOADR = [&](int p, int ciq) {
    const unsigned short* xq = xblk + ((size_t)(b * 3 + ciq)) * (262144ull * 32) +
                               (size_t)p * (4096 * 32);
    #pragma unroll
    for (int ii = 0; ii < 11; ++ii) {
      const int idx = ii * 256 + tid;
      bf16x8 val = {0, 0, 0, 0, 0, 0, 0, 0};
      if (idx < 2640) {
        const int row = idx / 264;
        const int rem = idx - row * 264;
        const int x = rem >> 2;
        const int cq = rem & 3;
        const int gy = y0 + row - 1, gx = x - 1;
        if ((unsigned)gy < 64u && (unsigned)gx < 64u)
          val = *(const bf16x8*)(xq + (size_t)(gy * 64 + gx) * 32 + cq * 8);
      }
      rv[ii] = val;
    }
  };
  auto WRITEB = [&]() {
    #pragma unroll
    for (int ii = 0; ii < 11; ++ii) {
      const int idx = ii * 256 + tid;
      if (idx < 2640) {
        const int row = idx / 264;
        const int rem = idx - row * 264;
        const int x = rem >> 2;
        const int cq = rem & 3;
        *(bf16x8*)&XT[row * 2376 + x * 36 + cq * 8] = rv[ii];
      }
    }
  };

  auto C2 = [&](int dzA, int dzB, int ciq) {
    #pragma unroll
    for (int dy = 0; dy < 3; ++dy) {
      #pragma unroll
      for (int dx = 0; dx < 3; ++dx) {
        const unsigned short* wpA =
            wt2 + ((size_t)((((dzA * 3 + dy) * 3 + dx) * 3 + ciq) * 4 + oct)) * 256;
        const unsigned short* wpB =
            wt2 + ((size_t)((((dzB * 3 + dy) * 3 + dx) * 3 + ciq) * 4 + oct)) * 256;
        bf16x8 wA0 = *(const bf16x8*)(wpA + r * 8);
        bf16x8 wA1 = *(const bf16x8*)(wpA + 128 + r * 8);
        bf16x8 wB0 = *(const bf16x8*)(wpB + r * 8);
        bf16x8 wB1 = *(const bf16x8*)(wpB + 128 + r * 8);
        #pragma unroll
        for (int ry = 0; ry < 2; ++ry) {
          const int lrow = w * 2 + ry + dy;
          #pragma unroll
          for (int xc = 0; xc < 4; ++xc) {
            bf16x8 af = *(const bf16x8*)&XT[lrow * 2376 + (xc * 16 + r + dx) * 36 + oct * 8];
            acc0[ry][xc][0] = __builtin_amdgcn_mfma_f32_16x16x32_bf16(af, wA0, acc0[ry][xc][0], 0, 0, 0);
            acc0[ry][xc][1] = __builtin_amdgcn_mfma_f32_16x16x32_bf16(af, wA1, acc0[ry][xc][1], 0, 0, 0);
            acc1[ry][xc][0] = __builtin_amdgcn_mfma_f32_16x16x32_bf16(af, wB0, acc1[ry][xc][0], 0, 0, 0);
            acc1[ry][xc][1] = __builtin_amdgcn_mfma_f32_16x16x32_bf16(af, wB1, acc1[ry][xc][1], 0, 0, 0);
          }
        }
      }
    }
  };

  auto C1 = [&](f32x4 (&A)[2][4][2], int dz, int ciq) {
    #pragma unroll
    for (int dy = 0; dy < 3; ++dy) {
      #pragma unroll
      for (int dx = 0; dx < 3; ++dx) {
        const unsigned short* wp =
            wt2 + ((size_t)((((dz * 3 + dy) * 3 + dx) * 3 + ciq) * 4 + oct)) * 256;
        bf16x8 w0 = *(const bf16x8*)(wp + r * 8);
        bf16x8 w1 = *(const bf16x8*)(wp + 128 + r * 8);
        #pragma unroll
        for (int ry = 0; ry < 2; ++ry) {
          const int lrow = w * 2 + ry + dy;
          #pragma unroll
          for (int xc = 0; xc < 4; ++xc) {
            bf16x8 af = *(const bf16x8*)&XT[lrow * 2376 + (xc * 16 + r + dx) * 36 + oct * 8];
            A[ry][xc][0] = __builtin_amdgcn_mfma_f32_16x16x32_bf16(af, w0, A[ry][xc][0], 0, 0, 0);
            A[ry][xc][1] = __builtin_amdgcn_mfma_f32_16x16x32_bf16(af, w1, A[ry][xc][1], 0, 0, 0);
          }
        }
      }
    }
  };

  // stage list: plane index ps (0..3) x ciq (0..2), skipping invalid planes
  int sps[12], scq[12], ns = 0;
  #pragma unroll
  for (int ps = 0; ps < 4; ++ps) {
    if ((unsigned)(z0 - 1 + ps) > 63u) continue;
    for (int ciq = 0; ciq < 3; ++ciq) { sps[ns] = ps; scq[ns] = ciq; ++ns; }
  }

  LOADR(z0 - 1 + sps[0], scq[0]);
  WRITEB();
  __syncthreads();
  for (int t = 0; t < ns; ++t) {
    if (t + 1 < ns) LOADR(z0 - 1 + sps[t + 1], scq[t + 1]);   // issue early
    const int ps = sps[t];
    if (ps == 0)      C1(acc0, 0, scq[t]);              // only z0, dz=0
    else if (ps == 3) C1(acc1, 2, scq[t]);              // only z0+1, dz=2
    else              C2(ps, ps - 1, scq[t]);           // both
    __syncthreads();                                    // all done reading XT
    if (t + 1 < ns) {
      WRITEB();                                         // loads landed under compute
      __syncthreads();
    }
  }

  float invc[2], shc[2], bic[2];
  #pragma unroll
  for (int ct = 0; ct < 2; ++ct) {
    const int co = ct * 16 + r;
    const float iv = gamma[co] * rsqrtf(var[co] + 1e-5f);
    invc[ct] = iv;
    shc[ct] = beta[co] - mean[co] * iv;
    bic[ct] = cb[co];
  }

  auto STO = [&](f32x4 (&A)[2][4][2], int z) {
    #pragma unroll
    for (int ct = 0; ct < 2; ++ct) {
      float* oc = out + (((size_t)(b * CH + ct * 16 + r)) << 18) + ((size_t)z << 12);
      #pragma unroll
      for (int ry = 0; ry < 2; ++ry) {
        const int y = y0 + w * 2 + ry;
        #pragma unroll
        for (int xc = 0; xc < 4; ++xc) {
          const f32x4 a = A[ry][xc][ct];
          float4 st;
          st.x = fmaxf(0.f, (a[0] + bic[ct]) * invc[ct] + shc[ct]);
          st.y = fmaxf(0.f, (a[1] + bic[ct]) * invc[ct] + shc[ct]);
          st.z = fmaxf(0.f, (a[2] + bic[ct]) * invc[ct] + shc[ct]);
          st.w = fmaxf(0.f, (a[3] + bic[ct]) * invc[ct] + shc[ct]);
          *(float4*)(oc + (size_t)y * 64 + xc * 16 + oct * 4) = st;
        }
      }
    }
  };
  STO(acc0, z0);
  STO(acc1, z0 + 1);
}

extern "C" void kernel_launch(void* const* d_in, const int* in_sizes, int n_in,
                              void* d_out, int out_size, void* d_ws, size_t ws_size,
                              hipStream_t stream) {
  const float* q     = (const float*)d_in[0];
  const float* k     = (const float*)d_in[1];
  const float* v     = (const float*)d_in[2];
  const float* cw    = (const float*)d_in[3];
  const float* cb    = (const float*)d_in[4];
  const float* gamma = (const float*)d_in[5];
  const float* beta  = (const float*)d_in[6];
  const float* mean  = (const float*)d_in[7];
  const float* var   = (const float*)d_in[8];

  unsigned short* xblk = (unsigned short*)d_ws;                             // 96 MiB
  unsigned short* y0b  = (unsigned short*)((char*)d_ws + (96ull  << 20));   // 16 MiB
  _Float16*       qT   = (_Float16*)((char*)d_ws + (112ull << 20));         // 16 MiB
  _Float16*       kT   = (_Float16*)((char*)d_ws + (128ull << 20));         // 16 MiB
  _Float16*       vT   = (_Float16*)((char*)d_ws + (144ull << 20));         // 16 MiB
  unsigned short* wt2  = (unsigned short*)((char*)d_ws + (160ull << 20));   // 166 KB
  // qF/kF/vF alias the xblk[b=1] region (bytes 48..96 MiB): per batch they
  // are written by trans_b and fully consumed by attn<1>/<2>_b BEFORE
  // repack_b1 overwrites that region (stream order). repack_b0 writes only
  // xblk[b=0] (bytes 0..48 MiB), disjoint.
  _Float16* qF = (_Float16*)((char*)d_ws + (48ull << 20));                  // 16 MiB
  _Float16* kF = (_Float16*)((char*)d_ws + (64ull << 20));                  // 16 MiB
  _Float16* vF = (_Float16*)((char*)d_ws + (80ull << 20));                  // 16 MiB
  // y1/y2 alias kT/vT (dead after attn<0> of the same batch)
  unsigned short* y1b = (unsigned short*)kT;
  unsigned short* y2b = (unsigned short*)vT;
  float* out = (float*)d_out;

  hipLaunchKernelGGL(wprep, dim3(324), dim3(256), 0, stream, cw, wt2);
  for (int b = 0; b < 2; ++b) {
    hipLaunchKernelGGL(trans_dwh, dim3(2048), dim3(256), 0, stream,
                       q, k, v, qT, kT, vT, qF, kF, vF, b);
    hipLaunchKernelGGL((attn_mfma<0>), dim3(2048), dim3(256), 0, stream,
                       qT, kT, vT, qF, kF, vF, y0b);
    hipLaunchKernelGGL((attn_mfma<1>), dim3(2048), dim3(256), 0, stream,
                       qT, kT, vT, qF, kF, vF, y1b);
    hipLaunchKernelGGL((attn_mfma<2>), dim3(2048), dim3(256), 0, stream,
                       qT, kT, vT, qF, kF, vF, y2b);
    hipLaunchKernelGGL(repack_all, dim3(1536), dim3(256), 0, stream,
                       y0b, y1b, y2b, xblk, b);
  }
  hipLaunchKernelGGL(conv_mfma, dim3(512), dim3(256), 0, stream,
                     xblk, wt2, cb, gamma, beta, mean, var, out);
}

// Round 18
// 332.516 us; speedup vs baseline: 2.0605x; 2.0605x over previous
//
#include <hip/hip_runtime.h>
#include <hip/hip_bf16.h>

// BS=2, C=32, S=64.
// ws: [0, 96 MiB)    xblk bf16 [b][ciq][64^3][32]  (blocked channels-last)
//     [48, 96 MiB)   (alias) qF,kF,vF f16 [c][h][w][d] — live only between
//                    trans_b and repack_b of the same batch (xblk[b=1] region)
//     [96, 112 MiB)  y0   bf16 [c][s][4096]
//     [112,128 MiB)  qT   f16  [c][d][w][h]
//     [128,144 MiB)  kT   f16  (aliased as y1 after attn<0>)
//     [144,160 MiB)  vT   f16  (aliased as y2 after attn<0>)
//     [160 MiB,+166K) wt2 bf16 [tap][ciq][oct][co][8]
// out: (2,32,64,64,64) fp32.

#define CH 32

typedef __attribute__((ext_vector_type(8))) _Float16 f16x8;
typedef __attribute__((ext_vector_type(4))) _Float16 f16x4;
typedef __attribute__((ext_vector_type(8))) short bf16x8;
typedef __attribute__((ext_vector_type(4))) float f32x4;

static __device__ __forceinline__ unsigned short f2bf(float f) {
  union { float f; unsigned u; } x; x.f = f;
  unsigned r = x.u + 0x7fff + ((x.u >> 16) & 1);   // RNE
  return (unsigned short)(r >> 16);
}

// ---------------------------------------------------------------------------
// trans_dwh: q/k/v f32 [c][h][w][d] -> f16 [c][d][w][h] (qT/kT/vT for BR0)
// AND f16 same-layout copies [c][h][w][d] (qF/kF/vF for BR1/2).
// ---------------------------------------------------------------------------
__global__ __launch_bounds__(256) void trans_dwh(const float* __restrict__ q,
                                                 const float* __restrict__ k,
                                                 const float* __restrict__ v,
                                                 _Float16* __restrict__ qT,
                                                 _Float16* __restrict__ kT,
                                                 _Float16* __restrict__ vT,
                                                 _Float16* __restrict__ qF,
                                                 _Float16* __restrict__ kF,
                                                 _Float16* __restrict__ vF,
                                                 int b) {
  __shared__ __align__(16) _Float16 Ls[64 * 72];
  const int blk = blockIdx.x;          // 2048 = c*64 + w
  const int c = blk >> 6;
  const int w = blk & 63;
  const int tid = threadIdx.x;
  const size_t bc = (size_t)(b * CH + c);
  const float* srcs[3] = {q, k, v};
  _Float16* dsts[3] = {qT, kT, vT};
  _Float16* dstsF[3] = {qF, kF, vF};
  const int h = tid >> 2, dq = tid & 3;

  for (int tz = 0; tz < 3; ++tz) {
    const float* sp = srcs[tz] + bc * 262144 + (size_t)h * 4096 + (size_t)w * 64;
    float4 ld[4];
    #pragma unroll
    for (int pp = 0; pp < 4; ++pp) {
      const int d0 = dq * 16 + pp * 4;
      ld[pp] = *(const float4*)(sp + d0);
      Ls[(d0 + 0) * 72 + h] = (_Float16)ld[pp].x;
      Ls[(d0 + 1) * 72 + h] = (_Float16)ld[pp].y;
      Ls[(d0 + 2) * 72 + h] = (_Float16)ld[pp].z;
      Ls[(d0 + 3) * 72 + h] = (_Float16)ld[pp].w;
    }
    // same-layout f16 copy: contiguous 16B x2 per thread
    {
      _Float16* fp = dstsF[tz] + (size_t)c * 262144 + (size_t)h * 4096 +
                     (size_t)w * 64 + dq * 16;
      f16x8 lo8 = {(_Float16)ld[0].x, (_Float16)ld[0].y, (_Float16)ld[0].z, (_Float16)ld[0].w,
                   (_Float16)ld[1].x, (_Float16)ld[1].y, (_Float16)ld[1].z, (_Float16)ld[1].w};
      f16x8 hi8 = {(_Float16)ld[2].x, (_Float16)ld[2].y, (_Float16)ld[2].z, (_Float16)ld[2].w,
                   (_Float16)ld[3].x, (_Float16)ld[3].y, (_Float16)ld[3].z, (_Float16)ld[3].w};
      *(f16x8*)(fp) = lo8;
      *(f16x8*)(fp + 8) = hi8;
    }
    __syncthreads();
    _Float16* dp = dsts[tz] + (size_t)c * 262144 + (size_t)w * 64;
    #pragma unroll
    for (int p = 0; p < 2; ++p) {
      const int idx = p * 256 + tid;
      const int d = idx >> 3, o = (idx & 7) * 8;
      *(f16x8*)(dp + (size_t)d * 4096 + o) = *(const f16x8*)&Ls[d * 72 + o];
    }
    __syncthreads();
  }
}

// ---------------------------------------------------------------------------
// attn core (shared by BR0 kernel and merged BR1/2 kernel).
// Qh/Kh row-major [token][feat]; Vh: BR0 -> Vt[t][j], BR1/2 -> Vh[j][t].
// ---------------------------------------------------------------------------
__device__ __forceinline__ void attn_core(_Float16 (&Qh)[64][72],
                                          _Float16 (&Kh)[64][72],
                                          _Float16 (&Vh)[64][72],
                                          bool v_transposed,
                                          unsigned short* __restrict__ ydst,
                                          int c, int s, int tid) {
  const int w = tid >> 6;
  const int lane = tid & 63;
  const int r = lane & 15;
  const int oct = lane >> 4;

  f32x4 sc[4];
  #pragma unroll
  for (int jt = 0; jt < 4; ++jt) sc[jt] = (f32x4){0.f, 0.f, 0.f, 0.f};
  f16x8 aq0 = *(const f16x8*)&Qh[w * 16 + r][oct * 8];
  f16x8 aq1 = *(const f16x8*)&Qh[w * 16 + r][32 + oct * 8];
  #pragma unroll
  for (int jt = 0; jt < 4; ++jt) {
    f16x8 bk0 = *(const f16x8*)&Kh[jt * 16 + r][oct * 8];
    f16x8 bk1 = *(const f16x8*)&Kh[jt * 16 + r][32 + oct * 8];
    sc[jt] = __builtin_amdgcn_mfma_f32_16x16x32_f16(aq0, bk0, sc[jt], 0, 0, 0);
    sc[jt] = __builtin_amdgcn_mfma_f32_16x16x32_f16(aq1, bk1, sc[jt], 0, 0, 0);
  }

  float P[4][4];
  #pragma unroll
  for (int reg = 0; reg < 4; ++reg) {
    float mx = fmaxf(fmaxf(sc[0][reg], sc[1][reg]), fmaxf(sc[2][reg], sc[3][reg]));
    mx = fmaxf(mx, __shfl_xor(mx, 1));
    mx = fmaxf(mx, __shfl_xor(mx, 2));
    mx = fmaxf(mx, __shfl_xor(mx, 4));
    mx = fmaxf(mx, __shfl_xor(mx, 8));
    float e[4], sum = 0.f;
    #pragma unroll
    for (int jt = 0; jt < 4; ++jt) { e[jt] = __expf(sc[jt][reg] - mx); sum += e[jt]; }
    sum += __shfl_xor(sum, 1);
    sum += __shfl_xor(sum, 2);
    sum += __shfl_xor(sum, 4);
    sum += __shfl_xor(sum, 8);
    const float inv = 1.f / sum;
    #pragma unroll
    for (int jt = 0; jt < 4; ++jt) P[reg][jt] = e[jt] * inv;
  }

  #pragma unroll
  for (int reg = 0; reg < 4; ++reg)
    #pragma unroll
    for (int jt = 0; jt < 4; ++jt)
      Qh[w * 16 + oct * 4 + reg][jt * 16 + r] = (_Float16)P[reg][jt];

  f16x8 ap0 = *(const f16x8*)&Qh[w * 16 + r][oct * 8];
  f16x8 ap1 = *(const f16x8*)&Qh[w * 16 + r][32 + oct * 8];
  f32x4 ot[4];
  #pragma unroll
  for (int tt = 0; tt < 4; ++tt) {
    ot[tt] = (f32x4){0.f, 0.f, 0.f, 0.f};
    f16x8 bv0, bv1;
    if (v_transposed) {
      bv0 = *(const f16x8*)&Vh[tt * 16 + r][oct * 8];
      bv1 = *(const f16x8*)&Vh[tt * 16 + r][32 + oct * 8];
    } else {
      #pragma unroll
      for (int e = 0; e < 8; ++e) {
        bv0[e] = Vh[oct * 8 + e][tt * 16 + r];
        bv1[e] = Vh[32 + oct * 8 + e][tt * 16 + r];
      }
    }
    ot[tt] = __builtin_amdgcn_mfma_f32_16x16x32_f16(ap0, bv0, ot[tt], 0, 0, 0);
    ot[tt] = __builtin_amdgcn_mfma_f32_16x16x32_f16(ap1, bv1, ot[tt], 0, 0, 0);
  }

  __syncthreads();
  unsigned short* Ot = (unsigned short*)&Kh[0][0];   // stride 72
  #pragma unroll
  for (int tt = 0; tt < 4; ++tt)
    #pragma unroll
    for (int reg = 0; reg < 4; ++reg)
      Ot[(size_t)(w * 16 + oct * 4 + reg) * 72 + tt * 16 + r] = f2bf(ot[tt][reg]);
  __syncthreads();

  {
    const int i = tid >> 2, seg = tid & 3;
    const unsigned short* src = Ot + (size_t)i * 72 + seg * 16;
    bf16x8 a0 = *(const bf16x8*)(src);
    bf16x8 a1 = *(const bf16x8*)(src + 8);
    unsigned short* dst = ydst + ((size_t)(c * 64 + s)) * 4096 + tid * 16;
    *(bf16x8*)(dst) = a0;
    *(bf16x8*)(dst + 8) = a1;
  }
}

// BR0: reads pre-transposed qT/kT/vT planes (fully coalesced), V transposed.
__global__ __launch_bounds__(256) void attn0(const _Float16* __restrict__ qT,
                                             const _Float16* __restrict__ kT,
                                             const _Float16* __restrict__ vT,
                                             unsigned short* __restrict__ y0b) {
  __shared__ __align__(16) _Float16 Qh[64][72];
  __shared__ __align__(16) _Float16 Kh[64][72];
  __shared__ __align__(16) _Float16 Vh[64][72];

  const int blk0 = blockIdx.x;
  const int blk = ((blk0 & 7) << 8) | (blk0 >> 3);   // XCD chunk (2048 = 8*256)
  const int s = blk & 63;
  const int c = blk >> 6;
  const int tid = threadIdx.x;

  const _Float16* qp = qT + ((size_t)c * 64 + s) * 4096;
  const _Float16* kp = kT + ((size_t)c * 64 + s) * 4096;
  const _Float16* vp = vT + ((size_t)c * 64 + s) * 4096;
  #pragma unroll
  for (int ii = 0; ii < 2; ++ii) {
    const int idx = ii * 256 + tid;
    const int row = idx >> 3, ch = (idx & 7) * 8;
    *(f16x8*)&Qh[row][ch] = *(const f16x8*)(qp + row * 64 + ch);
    *(f16x8*)&Kh[row][ch] = *(const f16x8*)(kp + row * 64 + ch);
    *(f16x8*)&Vh[row][ch] = *(const f16x8*)(vp + row * 64 + ch);   // Vt[t][j]
  }
  __syncthreads();
  attn_core(Qh, Kh, Vh, true, y0b, c, s, tid);
}

// Merged BR1+BR2 (grid 4096): both read qF/kF/vF; write y1b / y2b.
// Safe to merge: neither reads kT/vT (overwritten by y1b/y2b aliasing).
__global__ __launch_bounds__(256) void attn12(const _Float16* __restrict__ qF,
                                              const _Float16* __restrict__ kF,
                                              const _Float16* __restrict__ vF,
                                              unsigned short* __restrict__ y1b,
                                              unsigned short* __restrict__ y2b) {
  __shared__ __align__(16) _Float16 Qh[64][72];
  __shared__ __align__(16) _Float16 Kh[64][72];
  __shared__ __align__(16) _Float16 Vh[64][72];

  const int blk0 = blockIdx.x;
  const int blk = ((blk0 & 7) << 9) | (blk0 >> 3);   // XCD chunk (4096 = 8*512)
  const int br2 = blk >> 11;                         // 0 -> BR1, 1 -> BR2
  const int inner = blk & 2047;
  const int s = inner & 63;
  const int c = inner >> 6;
  const int tid = threadIdx.x;

  const size_t base = (size_t)c * 262144;
  #pragma unroll
  for (int ii = 0; ii < 2; ++ii) {
    const int idx = ii * 256 + tid;
    const int row = idx >> 3, ch = (idx & 7) * 8;
    const size_t off = br2 ? ((size_t)s * 4096 + (size_t)row * 64 + ch)
                           : ((size_t)row * 4096 + (size_t)s * 64 + ch);
    *(f16x8*)&Qh[row][ch] = *(const f16x8*)(qF + base + off);
    *(f16x8*)&Kh[row][ch] = *(const f16x8*)(kF + base + off);
    *(f16x8*)&Vh[row][ch] = *(const f16x8*)(vF + base + off);      // Vh[j][t]
  }
  __syncthreads();
  attn_core(Qh, Kh, Vh, false, br2 ? y2b : y1b, c, s, tid);
}

// ---------------------------------------------------------------------------
// repack_all: all 3 branches in one dispatch (grid 1536 = br*512 + inner).
// ---------------------------------------------------------------------------
__global__ __launch_bounds__(256) void repack_all(const unsigned short* __restrict__ y0p,
                                                  const unsigned short* __restrict__ y1p,
                                                  const unsigned short* __restrict__ y2p,
                                                  unsigned short* __restrict__ xblk,
                                                  int b) {
  __shared__ unsigned short Ls[32 * 530];
  const int blk = blockIdx.x;        // 1536
  const int br = blk >> 9;           // 0..2
  const int inner = blk & 511;
  const int oc = inner & 7;
  const int z = inner >> 3;
  const int tid = threadIdx.x;
  const int c = tid & 31;
  const int w8 = tid >> 5;           // 0..7

  const unsigned short* ybr = (br == 0) ? y0p : (br == 1) ? y1p : y2p;

  size_t src;
  if (br == 2) src = ((size_t)(c * 64 + z)) * 4096 + (size_t)(oc * 8 + w8) * 64;
  else         src = ((size_t)(c * 64 + oc * 8 + w8)) * 4096 + (size_t)z * 64;

  #pragma unroll
  for (int kk = 0; kk < 8; ++kk) {
    bf16x8 vv = *(const bf16x8*)(ybr + src + kk * 8);
    #pragma unroll
    for (int e = 0; e < 8; ++e) {
      const int l = kk * 8 + e;
      const int li = (br == 0) ? (l * 8 + w8) : (w8 * 64 + l);
      Ls[c * 530 + li] = (unsigned short)vv[e];
    }
  }
  __syncthreads();

  unsigned short* xq = xblk + ((size_t)(b * 3 + br)) * 262144 * 32;
  #pragma unroll
  for (int p = 0; p < 2; ++p) {
    const int o = p * 256 + tid;
    bf16x8 o0, o1, o2, o3;
    #pragma unroll
    for (int e = 0; e < 8; ++e) {
      o0[e] = (short)Ls[(e)      * 530 + o];
      o1[e] = (short)Ls[(8 + e)  * 530 + o];
      o2[e] = (short)Ls[(16 + e) * 530 + o];
      o3[e] = (short)Ls[(24 + e) * 530 + o];
    }
    int sp;
    if (br == 0) sp = z * 4096 + (o >> 3) * 64 + oc * 8 + (o & 7);
    else         sp = z * 4096 + oc * 512 + o;
    unsigned short* dst = xq + (size_t)sp * 32;
    *(bf16x8*)(dst)      = o0;
    *(bf16x8*)(dst + 8)  = o1;
    *(bf16x8*)(dst + 16) = o2;
    *(bf16x8*)(dst + 24) = o3;
  }
}

// w[co][ci][dz][dy][dx] f32 -> wt2 bf16, idx = (((tap*3+ciq)*4+oct)*32 + co)*8 + e
__global__ __launch_bounds__(256) void wprep(const float* __restrict__ w,
                                             unsigned short* __restrict__ wt2) {
  int idx = blockIdx.x * 256 + threadIdx.x;
  if (idx >= 27 * 32 * 96) return;
  int tap = idx / 3072;
  int rem = idx - tap * 3072;
  int co = rem / 96, ci = rem - co * 96;
  int ciq = ci >> 5, oct = (ci >> 3) & 3, e = ci & 7;
  wt2[(((tap * 3 + ciq) * 4 + oct) * 32 + co) * 8 + e] =
      f2bf(w[((size_t)co * 96 + ci) * 27 + tap]);
}

// ---------------------------------------------------------------------------
// Z-PAIR LDS-staged implicit-GEMM conv — R8/R16 MEASURED KERNEL, VERBATIM.
// (256,2), grid 512, swizzle chunk 64, pad-36 tile, reg-roundtrip staging.
// Empirically pinned optimum: {1,2,3,4 blk/CU; gload_lds; T14} all worse.
// ---------------------------------------------------------------------------
__global__ __launch_bounds__(256, 2) void conv_mfma(const unsigned short* __restrict__ xblk,
                                                    const unsigned short* __restrict__ wt2,
                                                    const float* __restrict__ cb,
                                                    const float* __restrict__ gamma,
                                                    const float* __restrict__ beta,
                                                    const float* __restrict__ mean,
                                                    const float* __restrict__ var,
                                                    float* __restrict__ out) {
  __shared__ __align__(16) unsigned short XT[23760];   // 10*66*36 shorts

  const int blk0 = blockIdx.x;                       // 512
  const int blk = ((blk0 & 7) << 6) | (blk0 >> 3);   // XCD chunk (512 = 8*64)
  const int yt = blk & 7;
  const int zp = (blk >> 3) & 31;
  const int b = blk >> 8;                            // 0..1
  const int tid = threadIdx.x;
  const int w = tid >> 6;
  const int lane = tid & 63;
  const int r = lane & 15;
  const int oct = lane >> 4;
  const int y0 = yt * 8;
  const int z0 = zp * 2;

  f32x4 acc0[2][4][2], acc1[2][4][2];
  #pragma unroll
  for (int ry = 0; ry < 2; ++ry)
    #pragma unroll
    for (int xc = 0; xc < 4; ++xc)
      #pragma unroll
      for (int ct = 0; ct < 2; ++ct) {
        acc0[ry][xc][ct] = (f32x4){0.f, 0.f, 0.f, 0.f};
        acc1[ry][xc][ct] = (f32x4){0.f, 0.f, 0.f, 0.f};
      }

  auto STAGE = [&](int p, int ciq) {
    const unsigned short* xq = xblk + ((size_t)(b * 3 + ciq)) * (262144ull * 32) +
                               (size_t)p * (4096 * 32);
    #pragma unroll
    for (int ii = 0; ii < 11; ++ii) {
      const int idx = ii * 256 + tid;
      if (idx < 2640) {
        const int row = idx / 264;
        const int rem = idx - row * 264;
        const int x = rem >> 2;
        const int cq = rem & 3;
        const int gy = y0 + row - 1, gx = x - 1;
        bf16x8 val = {0, 0, 0, 0, 0, 0, 0, 0};
        if ((unsigned)gy < 64u && (unsigned)gx < 64u)
          val = *(const bf16x8*)(xq + (size_t)(gy * 64 + gx) * 32 + cq * 8);
        *(bf16x8*)&XT[row * 2376 + x * 36 + cq * 8] = val;
      }
    }
  };

  auto C2 = [&](int dzA, int dzB, int ciq) {
    #pragma unroll
    for (int dy = 0; dy < 3; ++dy) {
      #pragma unroll
      for (int dx = 0; dx < 3; ++dx) {
        const unsigned short* wpA =
            wt2 + ((size_t)((((dzA * 3 + dy) * 3 + dx) * 3 + ciq) * 4 + oct)) * 256;
        const unsigned short* wpB =
            wt2 + ((size_t)((((dzB * 3 + dy) * 3 + dx) * 3 + ciq) * 4 + oct)) * 256;
        bf16x8 wA0 = *(const bf16x8*)(wpA + r * 8);
        bf16x8 wA1 = *(const bf16x8*)(wpA + 128 + r * 8);
        bf16x8 wB0 = *(const bf16x8*)(wpB + r * 8);
        bf16x8 wB1 = *(const bf16x8*)(wpB + 128 + r * 8);
        #pragma unroll
        for (int ry = 0; ry < 2; ++ry) {
          const int lrow = w * 2 + ry + dy;
          #pragma unroll
          for (int xc = 0; xc < 4; ++xc) {
            bf16x8 af = *(const bf16x8*)&XT[lrow * 2376 + (xc * 16 + r + dx) * 36 + oct * 8];
            acc0[ry][xc][0] = __builtin_amdgcn_mfma_f32_16x16x32_bf16(af, wA0, acc0[ry][xc][0], 0, 0, 0);
            acc0[ry][xc][1] = __builtin_amdgcn_mfma_f32_16x16x32_bf16(af, wA1, acc0[ry][xc][1], 0, 0, 0);
            acc1[ry][xc][0] = __builtin_amdgcn_mfma_f32_16x16x32_bf16(af, wB0, acc1[ry][xc][0], 0, 0, 0);
            acc1[ry][xc][1] = __builtin_amdgcn_mfma_f32_16x16x32_bf16(af, wB1, acc1[ry][xc][1], 0, 0, 0);
          }
        }
      }
    }
  };

  auto C1 = [&](f32x4 (&A)[2][4][2], int dz, int ciq) {
    #pragma unroll
    for (int dy = 0; dy < 3; ++dy) {
      #pragma unroll
      for (int dx = 0; dx < 3; ++dx) {
        const unsigned short* wp =
            wt2 + ((size_t)((((dz * 3 + dy) * 3 + dx) * 3 + ciq) * 4 + oct)) * 256;
        bf16x8 w0 = *(const bf16x8*)(wp + r * 8);
        bf16x8 w1 = *(const bf16x8*)(wp + 128 + r * 8);
        #pragma unroll
        for (int ry = 0; ry < 2; ++ry) {
          const int lrow = w * 2 + ry + dy;
          #pragma unroll
          for (int xc = 0; xc < 4; ++xc) {
            bf16x8 af = *(const bf16x8*)&XT[lrow * 2376 + (xc * 16 + r + dx) * 36 + oct * 8];
            A[ry][xc][0] = __builtin_amdgcn_mfma_f32_16x16x32_bf16(af, w0, A[ry][xc][0], 0, 0, 0);
            A[ry][xc][1] = __builtin_amdgcn_mfma_f32_16x16x32_bf16(af, w1, A[ry][xc][1], 0, 0, 0);
          }
        }
      }
    }
  };

  #pragma unroll
  for (int ps = 0; ps < 4; ++ps) {
    const int p = z0 - 1 + ps;
    if ((unsigned)p > 63u) continue;   // uniform per block
    for (int ciq = 0; ciq < 3; ++ciq) {
      __syncthreads();
      STAGE(p, ciq);
      __syncthreads();
      if (ps == 0)      C1(acc0, 0, ciq);              // only z0, dz=0
      else if (ps == 3) C1(acc1, 2, ciq);              // only z0+1, dz=2
      else              C2(ps, ps - 1, ciq);           // both
    }
  }

  float invc[2], shc[2], bic[2];
  #pragma unroll
  for (int ct = 0; ct < 2; ++ct) {
    const int co = ct * 16 + r;
    const float iv = gamma[co] * rsqrtf(var[co] + 1e-5f);
    invc[ct] = iv;
    shc[ct] = beta[co] - mean[co] * iv;
    bic[ct] = cb[co];
  }

  auto STO = [&](f32x4 (&A)[2][4][2], int z) {
    #pragma unroll
    for (int ct = 0; ct < 2; ++ct) {
      float* oc = out + (((size_t)(b * CH + ct * 16 + r)) << 18) + ((size_t)z << 12);
      #pragma unroll
      for (int ry = 0; ry < 2; ++ry) {
        const int y = y0 + w * 2 + ry;
        #pragma unroll
        for (int xc = 0; xc < 4; ++xc) {
          const f32x4 a = A[ry][xc][ct];
          float4 st;
          st.x = fmaxf(0.f, (a[0] + bic[ct]) * invc[ct] + shc[ct]);
          st.y = fmaxf(0.f, (a[1] + bic[ct]) * invc[ct] + shc[ct]);
          st.z = fmaxf(0.f, (a[2] + bic[ct]) * invc[ct] + shc[ct]);
          st.w = fmaxf(0.f, (a[3] + bic[ct]) * invc[ct] + shc[ct]);
          *(float4*)(oc + (size_t)y * 64 + xc * 16 + oct * 4) = st;
        }
      }
    }
  };
  STO(acc0, z0);
  STO(acc1, z0 + 1);
}

extern "C" void kernel_launch(void* const* d_in, const int* in_sizes, int n_in,
                              void* d_out, int out_size, void* d_ws, size_t ws_size,
                              hipStream_t stream) {
  const float* q     = (const float*)d_in[0];
  const float* k     = (const float*)d_in[1];
  const float* v     = (const float*)d_in[2];
  const float* cw    = (const float*)d_in[3];
  const float* cb    = (const float*)d_in[4];
  const float* gamma = (const float*)d_in[5];
  const float* beta  = (const float*)d_in[6];
  const float* mean  = (const float*)d_in[7];
  const float* var   = (const float*)d_in[8];

  unsigned short* xblk = (unsigned short*)d_ws;                             // 96 MiB
  unsigned short* y0b  = (unsigned short*)((char*)d_ws + (96ull  << 20));   // 16 MiB
  _Float16*       qT   = (_Float16*)((char*)d_ws + (112ull << 20));         // 16 MiB
  _Float16*       kT   = (_Float16*)((char*)d_ws + (128ull << 20));         // 16 MiB
  _Float16*       vT   = (_Float16*)((char*)d_ws + (144ull << 20));         // 16 MiB
  unsigned short* wt2  = (unsigned short*)((char*)d_ws + (160ull << 20));   // 166 KB
  // qF/kF/vF alias the xblk[b=1] region (bytes 48..96 MiB): written by
  // trans_b, fully consumed by attn12_b BEFORE repack_b1 overwrites (stream
  // order); repack_b0 writes only xblk[b=0] (0..48 MiB), disjoint.
  _Float16* qF = (_Float16*)((char*)d_ws + (48ull << 20));                  // 16 MiB
  _Float16* kF = (_Float16*)((char*)d_ws + (64ull << 20));                  // 16 MiB
  _Float16* vF = (_Float16*)((char*)d_ws + (80ull << 20));                  // 16 MiB
  // y1/y2 alias kT/vT (dead after attn0 of the same batch)
  unsigned short* y1b = (unsigned short*)kT;
  unsigned short* y2b = (unsigned short*)vT;
  float* out = (float*)d_out;

  hipLaunchKernelGGL(wprep, dim3(324), dim3(256), 0, stream, cw, wt2);
  for (int b = 0; b < 2; ++b) {
    hipLaunchKernelGGL(trans_dwh, dim3(2048), dim3(256), 0, stream,
                       q, k, v, qT, kT, vT, qF, kF, vF, b);
    hipLaunchKernelGGL(attn0, dim3(2048), dim3(256), 0, stream, qT, kT, vT, y0b);
    hipLaunchKernelGGL(attn12, dim3(4096), dim3(256), 0, stream,
                       qF, kF, vF, y1b, y2b);
    hipLaunchKernelGGL(repack_all, dim3(1536), dim3(256), 0, stream,
                       y0b, y1b, y2b, xblk, b);
  }
  hipLaunchKernelGGL(conv_mfma, dim3(512), dim3(256), 0, stream,
                     xblk, wt2, cb, gamma, beta, mean, var, out);
}